// Round 2
// baseline (54.752 us; speedup 1.0000x reference)
//
#include <hip/hip_runtime.h>

// QConv1D quantum-circuit conv, analytically collapsed.
//
// Shapes: x (16, 2, 512) f32, weight (8, 8, 2) f32, out (16, 8, 509) f32.
// NQ = 8 qubits, LAYERS = 2, K = 4, STRIDE/DIL = 1, PAD = 0.
//
// Math: encode RY(x_q) + layer-0 RY(w0_q) fold into a product state with
// per-qubit angle (x_q+w0_q)/2. The final CZ layer cancels under |psi|^2
// (diagonal +-1 commutes with diagonal Z^n). Layer-1 RY conjugates the
// Z^{\otimes 8} observable into M_q = cos(w1_q) Z - sin(w1_q) X. Then
// E = <phi| D_CZ (prod M_q) D_CZ |phi> contracts as a chain transfer
// matrix with a symmetric 3-value accumulator (t = [[1,1],[1,-1]] per side).
//
// CRITICAL reference quirk: `out.reshape(B, L_out, O)` reinterprets the
// (o-slowest) flat simulate output with b' slowest — a genuine index
// scramble. out[b',o',l'] = E(o,b,l) with r = b'*L_out*O + l'*O + o',
// o = r/(B*L_out), b = (r%(B*L_out))/L_out, l = r%L_out.

#define BATCH 16
#define CIN   2
#define LIN   512
#define KW    4
#define OCH   8
#define NQ    8
#define LOUT  509                    // LIN - KW + 1
#define NTOT  (BATCH * LOUT)         // 8144
#define NOUT  (OCH * NTOT)           // 65152

__global__ __launch_bounds__(256) void qconv_kernel(
    const float* __restrict__ x,
    const float* __restrict__ w,
    float* __restrict__ out)
{
    int idx = blockIdx.x * 256 + threadIdx.x;
    if (idx >= NOUT) return;

    // idx is the output flat index in (b', o', l') layout == b'*O*LOUT + o'*LOUT + l'.
    // The simulate-flat index r equals b'*LOUT*O + l'*O + o' (see header comment).
    int lp = idx % LOUT;
    int tp = idx / LOUT;
    int op = tp % OCH;
    int bp = tp / OCH;
    int r  = bp * (LOUT * OCH) + lp * OCH + op;

    int o = r / NTOT;
    int n = r % NTOT;
    int b = n / LOUT;
    int l = n % LOUT;

    const float* wo = w + o * (NQ * 2);          // weight[o, q, layer]
    const float* xb = x + b * (CIN * LIN) + l;   // x[b, c, l + k]

    float A00 = 0.f, A01 = 0.f, A11 = 0.f;

    #pragma unroll
    for (int q = 0; q < NQ; ++q) {
        const int c = q >> 2;        // q = c*K + k
        const int k = q & 3;
        float xv = xb[c * LIN + k];

        float a  = 0.5f * (xv + wo[q * 2 + 0]);
        float w1 = wo[q * 2 + 1];

        float ca = __cosf(a),  sa = __sinf(a);
        float cw = __cosf(w1), sw = __sinf(w1);

        // V_q[z,z'] = p[z] p[z'] * M[z,z'],  M = [[cw,-sw],[-sw,-cw]], p=(ca,sa)
        float W00 =  ca * ca * cw;
        float W01 = -ca * sa * sw;
        float W11 = -sa * sa * cw;

        if (q == 0) {
            A00 = W00; A01 = W01; A11 = W11;
        } else {
            // B = t A t with t = [[1,1],[1,-1]] (symmetric A -> 3 values)
            float B00 = A00 + 2.f * A01 + A11;
            float B01 = A00 - A11;
            float B11 = A00 - 2.f * A01 + A11;
            A00 = W00 * B00;
            A01 = W01 * B01;
            A11 = W11 * B11;
        }
    }

    out[idx] = A00 + 2.f * A01 + A11;   // sum over final (z,z')
}

extern "C" void kernel_launch(void* const* d_in, const int* in_sizes, int n_in,
                              void* d_out, int out_size, void* d_ws, size_t ws_size,
                              hipStream_t stream) {
    const float* x = (const float*)d_in[0];
    const float* w = (const float*)d_in[1];
    float* out = (float*)d_out;

    const int block = 256;
    const int grid = (NOUT + block - 1) / block;   // 255
    qconv_kernel<<<grid, block, 0, stream>>>(x, w, out);
}

// Round 3
// 54.518 us; speedup vs baseline: 1.0043x; 1.0043x over previous
//
#include <hip/hip_runtime.h>

// QConv1D quantum-circuit conv, analytically collapsed.
//
// Shapes: x (16, 2, 512) f32, weight (8, 8, 2) f32, out (16, 8, 509) f32.
// NQ = 8 qubits, LAYERS = 2, K = 4, STRIDE/DIL = 1, PAD = 0.
//
// Math: encode RY(x_q) + layer-0 RY(w0_q) fold into a product state with
// per-qubit angle (x_q+w0_q)/2. The final CZ layer cancels under |psi|^2.
// Layer-1 RY conjugates Z^{\otimes 8} into M_q = cos(w1_q) Z - sin(w1_q) X.
// E = <phi| D_CZ (prod M_q) D_CZ |phi> contracts as a chain transfer matrix
// with a symmetric 3-value accumulator (t = [[1,1],[1,-1]] per side).
//
// Reference quirk: `out.reshape(B, L_out, O)` reinterprets the (o-slowest)
// simulate output with b' slowest — a real index scramble:
// out[b',o',l'] = E(o,b,l), r = b'*L_out*O + l'*O + o',
// o = r/(B*L_out), b = (r%(B*L_out))/L_out, l = r%L_out.
//
// Perf note (R2 counters): measured dur is dominated by the harness's 256 MB
// d_ws poison fill (~39.7 us at 84% HBM peak) + graph overhead; the kernel
// itself is single-digit us and latency-bound at ~1 wave/SIMD (65k threads
// over 256 CUs). This round: weight loads as 4x float4 (64B-aligned) and all
// x loads hoisted ahead of the trig chain to cut exposed load latency.

#define BATCH 16
#define CIN   2
#define LIN   512
#define KW    4
#define OCH   8
#define NQ    8
#define LOUT  509                    // LIN - KW + 1
#define NTOT  (BATCH * LOUT)         // 8144
#define NOUT  (OCH * NTOT)           // 65152

__global__ __launch_bounds__(256) void qconv_kernel(
    const float* __restrict__ x,
    const float* __restrict__ w,
    float* __restrict__ out)
{
    int idx = blockIdx.x * 256 + threadIdx.x;
    if (idx >= NOUT) return;

    // out flat (b',o',l') -> simulate flat r -> (o,b,l)
    int lp = idx % LOUT;
    int tp = idx / LOUT;
    int op = tp % OCH;
    int bp = tp / OCH;
    int r  = bp * (LOUT * OCH) + lp * OCH + op;

    int o = r / NTOT;
    int n = r % NTOT;
    int b = n / LOUT;
    int l = n % LOUT;

    // weight[o] = 16 contiguous floats, 64B aligned -> 4x float4
    const float4* w4 = (const float4*)(w + o * (NQ * 2));
    float4 wv0 = w4[0];   // (w0_q0, w1_q0, w0_q1, w1_q1)
    float4 wv1 = w4[1];
    float4 wv2 = w4[2];
    float4 wv3 = w4[3];

    float w0[NQ], w1[NQ];
    w0[0] = wv0.x; w1[0] = wv0.y; w0[1] = wv0.z; w1[1] = wv0.w;
    w0[2] = wv1.x; w1[2] = wv1.y; w0[3] = wv1.z; w1[3] = wv1.w;
    w0[4] = wv2.x; w1[4] = wv2.y; w0[5] = wv2.z; w1[5] = wv2.w;
    w0[6] = wv3.x; w1[6] = wv3.y; w0[7] = wv3.z; w1[7] = wv3.w;

    // hoist all x loads (independent, issue before trig chain)
    const float* xb = x + b * (CIN * LIN) + l;   // x[b, c, l + k]
    float xv[NQ];
    #pragma unroll
    for (int q = 0; q < NQ; ++q)
        xv[q] = xb[(q >> 2) * LIN + (q & 3)];

    float A00 = 0.f, A01 = 0.f, A11 = 0.f;

    #pragma unroll
    for (int q = 0; q < NQ; ++q) {
        float a  = 0.5f * (xv[q] + w0[q]);

        float ca = __cosf(a),     sa = __sinf(a);
        float cw = __cosf(w1[q]), sw = __sinf(w1[q]);

        // V_q[z,z'] = p[z] p[z'] * M[z,z'],  M = [[cw,-sw],[-sw,-cw]], p=(ca,sa)
        float W00 =  ca * ca * cw;
        float W01 = -ca * sa * sw;
        float W11 = -sa * sa * cw;

        if (q == 0) {
            A00 = W00; A01 = W01; A11 = W11;
        } else {
            // B = t A t with t = [[1,1],[1,-1]] (symmetric A -> 3 values)
            float B00 = A00 + 2.f * A01 + A11;
            float B01 = A00 - A11;
            float B11 = A00 - 2.f * A01 + A11;
            A00 = W00 * B00;
            A01 = W01 * B01;
            A11 = W11 * B11;
        }
    }

    out[idx] = A00 + 2.f * A01 + A11;   // sum over final (z,z')
}

extern "C" void kernel_launch(void* const* d_in, const int* in_sizes, int n_in,
                              void* d_out, int out_size, void* d_ws, size_t ws_size,
                              hipStream_t stream) {
    const float* x = (const float*)d_in[0];
    const float* w = (const float*)d_in[1];
    float* out = (float*)d_out;

    const int block = 256;
    const int grid = (NOUT + block - 1) / block;   // 255
    qconv_kernel<<<grid, block, 0, stream>>>(x, w, out);
}